// Round 7
// baseline (124.280 us; speedup 1.0000x reference)
//
#include <hip/hip_runtime.h>
#include <math.h>

#define EPSF 1e-8f

typedef _Float16 f16x8 __attribute__((ext_vector_type(8)));
typedef float    f32x4 __attribute__((ext_vector_type(4)));

constexpr int Bb = 8, Nn = 32768, Kk = 64, Dd = 64;

// GEMM-ified: C[k][n] = sum_d slots[k][d] * features[n][d] via
// v_mfma_f32_16x16x32_f16 with fp32 operands split hi/lo into f16
// (3 products: hi*hi + hi*lo + lo*hi ~ fp32-accurate).
//
// Round-7 revision. Evidence ledger:
//   r0 60.8 | r2 43.6 | r3 ~42 | r4 47.4 | r5 41.4 | r6 66.4
//   Invariant: VALUBusy*dur ~= 13.7us, MfmaUtil*dur ~= 2.3us across rounds
//   -> compute constant, only exposed stall varies.
//   r6 lesson: __syncthreads = s_waitcnt vmcnt(0) + barrier -> the flush/
//   barrier sequence drained 32KB of scattered stores to coherence twice
//   per block = +25us pure stall. The burst-write theory was NOT tested.
//   Still-open theory: writes (64MB in 64-256B segments @8MB stride) are
//   DRAM page-activate bound at ~2.2TB/s (fill kernel: sequential 6.5TB/s).
// Change (one variable vs r5): wave-PRIVATE LDS transpose staging of the
//   output -- NO barriers, NO vmcnt drains, stores never waited on.
//   Each wave: 2 phases x (stage 32k x 64n into its own padded LDS
//   quadrant, ds_read_b128 back k-row-major, global_store_dwordx4).
//   Per store instr: 4 k-rows x 256B contiguous (r5: 4 x 64B). 16 store
//   instrs/wave (was 64). Upstream identical to r5.
__global__ __launch_bounds__(256, 3) void attn_kernel(
    const float* __restrict__ features,
    const float* __restrict__ slots,
    const float* __restrict__ horizons,
    float* __restrict__ out)
{
    __shared__ float4 s_kp[Kk];        // (st, ss2_spatial, 1/(h+eps), pad)
    __shared__ f16x8 s_ahi[8][64];     // [t*2+c][lane] 8KB
    __shared__ f16x8 s_alo[8][64];     // 8KB
    __shared__ float s_w[4][32][68];   // per-wave staging, pad 68 (34KB)

    const int tid  = threadIdx.x;
    const int bid  = blockIdx.x;
    const int b    = bid >> 7;        // 128 blocks per batch
    const int blk  = bid & 127;
    const int lane = tid & 63;
    const int wid  = tid >> 6;
    const int m    = lane & 15;       // MFMA row/col lane index
    const int quad = lane >> 4;

    // ---- per-block slot constants, packed; unroll 4 caps reg spike ----
    if (tid < Kk) {
        const float4* sr = (const float4*)(slots + (size_t)(b * Kk + tid) * Dd);
        float st = 0.f, ss = 0.f;
        #pragma unroll 4
        for (int i = 0; i < 16; ++i) {
            float4 u = sr[i];
            if (i == 0) st = u.x;
            ss += u.x * u.x + u.y * u.y + u.z * u.z + u.w * u.w;
        }
        ss -= st * st;               // exclude time dim d0
        s_kp[tid] = make_float4(st, ss, 1.0f / (horizons[b * Kk + tid] + EPSF), 0.f);
    }

    // ---- cooperative A staging: thread (t=wid, lane) splits 2 fragments ----
    {
        const int t = wid;
        #pragma unroll
        for (int c = 0; c < 2; ++c) {
            const float* sp = slots + (size_t)(b * Kk + 16 * t + m) * Dd
                            + 32 * c + quad * 8;
            float4 u0 = *(const float4*)sp;
            float4 u1 = *(const float4*)(sp + 4);
            float fv[8] = {u0.x, u0.y, u0.z, u0.w, u1.x, u1.y, u1.z, u1.w};
            if (c == 0 && quad == 0) fv[0] = 0.0f;     // time dim out of dot
            f16x8 h8, l8;
            #pragma unroll
            for (int j = 0; j < 8; ++j) {
                float x = fv[j];
                _Float16 h = (_Float16)x;              // RN split
                _Float16 l = (_Float16)(x - (float)h);
                h8[j] = h;
                l8[j] = l;
            }
            s_ahi[t * 2 + c][lane] = h8;
            s_alo[t * 2 + c][lane] = l8;
        }
    }
    __syncthreads();

    const int n0 = (blk * 16 + wid * 4) * 16;   // 4 consecutive 16-n tiles, fused

    // ---- all 4 tiles' loads issued up front: 16 dwordx4 in flight ----
    float4 buf[4][4];
    #pragma unroll
    for (int it = 0; it < 4; ++it) {
        const float* fp = features + (((size_t)b << 15) + n0 + it * 16 + m) * Dd
                        + quad * 8;
        buf[it][0] = *(const float4*)(fp);
        buf[it][1] = *(const float4*)(fp + 4);
        buf[it][2] = *(const float4*)(fp + 32);
        buf[it][3] = *(const float4*)(fp + 36);
    }

    // ---- split all 4 tiles into f16 hi/lo fragments + fs2 ----
    f16x8 bh[4][2], bl[4][2];
    float ft[4], fs2[4];
    #pragma unroll
    for (int it = 0; it < 4; ++it) {
        const float f00 = buf[it][0].x;        // quad==0 lanes hold f[n][0]
        float s = 0.f;
        #pragma unroll
        for (int c = 0; c < 2; ++c) {
            float4 u0 = buf[it][2 * c];
            float4 u1 = buf[it][2 * c + 1];
            float fv[8] = {u0.x, u0.y, u0.z, u0.w, u1.x, u1.y, u1.z, u1.w};
            #pragma unroll
            for (int j = 0; j < 8; ++j) {
                float x = fv[j];
                s = fmaf(x, x, s);
                _Float16 h = (_Float16)x;
                _Float16 l = (_Float16)(x - (float)h);
                bh[it][c][j] = h;
                bl[it][c][j] = l;
            }
        }
        float f = __shfl(f00, m);              // lane m (<16, quad 0)
        s += __shfl_xor(s, 16);
        s += __shfl_xor(s, 32);                // full |f|^2 over 64 d
        ft[it]  = f;
        fs2[it] = fmaf(-f, f, s);              // spatial only
    }

    // ---- 96 MFMAs: per A-read, 4 independent 6-chains (16 chains total) ----
    f32x4 acc[4][4];                           // [it][t]
    #pragma unroll
    for (int t = 0; t < 4; ++t) {
        f16x8 ah0 = s_ahi[t * 2 + 0][lane];
        f16x8 ah1 = s_ahi[t * 2 + 1][lane];
        f16x8 al0 = s_alo[t * 2 + 0][lane];
        f16x8 al1 = s_alo[t * 2 + 1][lane];
        #pragma unroll
        for (int it = 0; it < 4; ++it) {
            f32x4 a = {0.f, 0.f, 0.f, 0.f};
            a = __builtin_amdgcn_mfma_f32_16x16x32_f16(ah0, bh[it][0], a, 0, 0, 0);
            a = __builtin_amdgcn_mfma_f32_16x16x32_f16(ah0, bl[it][0], a, 0, 0, 0);
            a = __builtin_amdgcn_mfma_f32_16x16x32_f16(al0, bh[it][0], a, 0, 0, 0);
            a = __builtin_amdgcn_mfma_f32_16x16x32_f16(ah1, bh[it][1], a, 0, 0, 0);
            a = __builtin_amdgcn_mfma_f32_16x16x32_f16(ah1, bl[it][1], a, 0, 0, 0);
            a = __builtin_amdgcn_mfma_f32_16x16x32_f16(al1, bh[it][1], a, 0, 0, 0);
            acc[it][t] = a;
        }
    }

    // ---- epilogue: one packed kparam read serves all 4 tiles ----
    float sum[4] = {0.f, 0.f, 0.f, 0.f};
    #pragma unroll
    for (int t = 0; t < 4; ++t) {
        #pragma unroll
        for (int r = 0; r < 4; ++r) {
            const int k = 16 * t + quad * 4 + r;   // C row
            float4 kp = s_kp[k];                   // st, ss2, rh
            #pragma unroll
            for (int it = 0; it < 4; ++it) {       // 4 independent trans chains
                float cross = acc[it][t][r];
                float dt  = ft[it] - kp.x;
                float dx2 = fmaf(-2.f, cross, fs2[it] + kp.y);
                dx2 = fmaxf(dx2, 0.f);
                float interval = fmaf(dt, dt, -dx2);
                float adist = __builtin_amdgcn_sqrtf(fabsf(interval) + EPSF);
                float cone  = (fabsf(dt) - __builtin_amdgcn_sqrtf(dx2 + EPSF)) * kp.z;
                float e  = __expf(2.0f * cone);    // tanh via exp, NaN-free
                float th = 1.0f - 2.0f * __builtin_amdgcn_rcpf(e + 1.0f);
                float logit = fmaf(0.5f, th, -adist);  // <= +0.5: exp safe
                float pe = __expf(logit);
                acc[it][t][r] = pe;                // overlay: acc reused as p
                sum[it] += pe;
            }
        }
    }
    float inv[4];
    #pragma unroll
    for (int it = 0; it < 4; ++it) {
        float s = sum[it];
        s += __shfl_xor(s, 16);
        s += __shfl_xor(s, 32);                    // total over 64 k
        inv[it] = __builtin_amdgcn_rcpf(s);
    }

    // ---- stores: wave-private LDS transpose, 2 phases, NO barriers ----
    // phase ph: stage k in [32ph,32ph+32) as s_w[wid][kr][n_local], then
    // flush: per instr, 4 k-rows x 256B contiguous dwordx4.
    float (*const my_w)[68] = s_w[wid];
    #pragma unroll
    for (int ph = 0; ph < 2; ++ph) {
        #pragma unroll
        for (int tt = 0; tt < 2; ++tt) {
            const int t = ph * 2 + tt;
            #pragma unroll
            for (int r = 0; r < 4; ++r) {
                const int kr = 16 * tt + quad * 4 + r;   // row within phase
                #pragma unroll
                for (int it = 0; it < 4; ++it) {
                    my_w[kr][it * 16 + m] = acc[it][t][r] * inv[it];
                }
            }
        }
        asm volatile("s_waitcnt lgkmcnt(0)" ::: "memory");  // in-wave RAW
        const int fr = lane >> 4;            // flush sub-row 0..3
        const int fc = (lane & 15) * 4;      // n_local base
        #pragma unroll
        for (int i = 0; i < 8; ++i) {
            const int kr = i * 4 + fr;
            const int k  = ph * 32 + kr;
            float4 v = *(const float4*)&my_w[kr][fc];
            *(float4*)(out + (((size_t)(b * Kk + k)) << 15) + n0 + fc) = v;
        }
        asm volatile("s_waitcnt lgkmcnt(0)" ::: "memory");  // reads before re-stage
    }
}

extern "C" void kernel_launch(void* const* d_in, const int* in_sizes, int n_in,
                              void* d_out, int out_size, void* d_ws, size_t ws_size,
                              hipStream_t stream) {
    const float* features = (const float*)d_in[0];
    const float* slots    = (const float*)d_in[1];
    const float* horizons = (const float*)d_in[2];
    float* out = (float*)d_out;

    // 1024 blocks x 256 thr = 4096 waves; each wave: 4 fused tiles of 16 n.
    // Store path: wave-private LDS transpose -> 256B-contiguous dwordx4.
    hipLaunchKernelGGL(attn_kernel, dim3(1024), dim3(256), 0, stream,
                       features, slots, horizons, out);
}